// Round 1
// baseline (58.507 us; speedup 1.0000x reference)
//
#include <hip/hip_runtime.h>
#include <hip/hip_bf16.h>

// Problem constants
#define B_DIM   32768
#define A_DIM   64
#define L_DIM   1024          // K
#define N_COLS  128           // 2*A
#define M_BLK   64
#define BDIM    256           // 4 waves
#define KCHUNK  256
#define NCHUNKS 4             // 1024 / 256
#define KSTEPS  8             // per chunk, K=32 per MFMA

using bf16x8 = __attribute__((ext_vector_type(8))) __bf16;
using f32x4  = __attribute__((ext_vector_type(4))) float;

// C[m][n] = sum_k F[m][k] * Wm[n][k];  out = tanh(C + bias[n])
// MFMA 16x16x32 bf16:
//   A-frag: lane l holds F[row = l&15][k = (l>>4)*8 + i], i=0..7 (contiguous)
//   B-frag: lane l holds Wm[n = l&15][k = (l>>4)*8 + i]      (contiguous)
//   C/D:    reg j of lane l = C[row = (l>>4)*4 + j][col = l&15]
__global__ __launch_bounds__(BDIM, 2)
void branched_policy_kernel(const float* __restrict__ F,
                            const float* __restrict__ W,
                            const float* __restrict__ bias,
                            float* __restrict__ out) {
    // W chunk in fragment order: unit v = (kstep*8 + colfrag)*64 + lane, 16B each
    __shared__ bf16x8 ldsB[4096];   // 64 KB

    const int tid  = threadIdx.x;
    const int lane = tid & 63;
    const int wave = tid >> 6;
    const int blk  = blockIdx.x;

    const int lcol = lane & 15;   // A-row / B-col within fragment
    const int lsub = lane >> 4;   // k subgroup 0..3

    // Per-lane feature row pointer (row read is 16 rows x 128B contiguous per wave-load)
    const int arow = blk * M_BLK + wave * 16 + lcol;
    const float* Fp = F + (size_t)arow * L_DIM + lsub * 8;

    f32x4 acc[8];
    #pragma unroll
    for (int c = 0; c < 8; ++c) acc[c] = (f32x4){0.f, 0.f, 0.f, 0.f};

    for (int ch = 0; ch < NCHUNKS; ++ch) {
        __syncthreads();
        // ---- stage W chunk -> LDS (f32 -> bf16, fragment order) ----
        #pragma unroll
        for (int i = 0; i < 16; ++i) {
            int v   = i * BDIM + tid;        // 0..4095
            int nl  = v & 15;
            int sub = (v >> 4) & 3;
            int c   = (v >> 6) & 7;
            int ks  = (v >> 9) & 7;
            int n   = c * 16 + nl;
            int k   = ch * KCHUNK + ks * 32 + sub * 8;
            const float4* wp = (const float4*)(W + (size_t)n * L_DIM + k);
            float4 w0 = wp[0];
            float4 w1 = wp[1];
            bf16x8 u;
            u[0] = (__bf16)w0.x; u[1] = (__bf16)w0.y;
            u[2] = (__bf16)w0.z; u[3] = (__bf16)w0.w;
            u[4] = (__bf16)w1.x; u[5] = (__bf16)w1.y;
            u[6] = (__bf16)w1.z; u[7] = (__bf16)w1.w;
            ldsB[v] = u;                     // ds_write_b128, lane-contiguous
        }
        __syncthreads();

        // ---- compute 8 K-steps over this chunk ----
        #pragma unroll
        for (int ks = 0; ks < KSTEPS; ++ks) {
            const float4* ap = (const float4*)(Fp + ch * KCHUNK + ks * 32);
            float4 a0 = ap[0];
            float4 a1 = ap[1];
            bf16x8 af;
            af[0] = (__bf16)a0.x; af[1] = (__bf16)a0.y;
            af[2] = (__bf16)a0.z; af[3] = (__bf16)a0.w;
            af[4] = (__bf16)a1.x; af[5] = (__bf16)a1.y;
            af[6] = (__bf16)a1.z; af[7] = (__bf16)a1.w;
            #pragma unroll
            for (int c = 0; c < 8; ++c) {
                bf16x8 bf = ldsB[(ks * 8 + c) * 64 + lane];  // ds_read_b128, conflict-free
                acc[c] = __builtin_amdgcn_mfma_f32_16x16x32_bf16(af, bf, acc[c], 0, 0, 0);
            }
        }
    }

    // ---- epilogue: bias + tanh + de-interleave to the two outputs ----
    const int orow0 = blk * M_BLK + wave * 16 + lsub * 4;
    float* out0 = out;
    float* out1 = out + (size_t)B_DIM * A_DIM;
    #pragma unroll
    for (int c = 0; c < 8; ++c) {
        int   n  = c * 16 + lcol;
        float bv = bias[n];
        float* obase = (n & 1) ? out1 : out0;
        int   aidx  = n >> 1;
        #pragma unroll
        for (int j = 0; j < 4; ++j) {
            float x = acc[c][j] + bv;
            // tanh(x) = 1 - 2/(exp(2x)+1); correct limits at +/-inf
            float e = __expf(2.0f * x);
            float t = 1.0f - 2.0f / (e + 1.0f);
            obase[(size_t)(orow0 + j) * A_DIM + aidx] = t;
        }
    }
}

extern "C" void kernel_launch(void* const* d_in, const int* in_sizes, int n_in,
                              void* d_out, int out_size, void* d_ws, size_t ws_size,
                              hipStream_t stream) {
    const float* F    = (const float*)d_in[0];  // [32768, 1024] f32
    const float* W    = (const float*)d_in[1];  // [64, 2, 1024] f32
    const float* bias = (const float*)d_in[2];  // [64, 2] f32
    float* outp       = (float*)d_out;          // [2][32768, 64] f32

    dim3 grid(B_DIM / M_BLK);   // 512 blocks
    dim3 block(BDIM);
    hipLaunchKernelGGL(branched_policy_kernel, grid, block, 0, stream,
                       F, W, bias, outp);
}